// Round 4
// baseline (370.592 us; speedup 1.0000x reference)
//
#include <hip/hip_runtime.h>
#include <cstdint>
#include <cstddef>

using half8  = __attribute__((ext_vector_type(8))) _Float16;
using half4  = __attribute__((ext_vector_type(4))) _Float16;
using float4v = __attribute__((ext_vector_type(4))) float;

#define CD 1024
#define M2 (1024 * 1024)

// async global->LDS, 16B per lane, wave-uniform LDS base + lane*16 dest
#define GLD16(gp, lp)                                                          \
    __builtin_amdgcn_global_load_lds(                                          \
        (const __attribute__((address_space(1))) void*)(gp),                   \
        (__attribute__((address_space(3))) void*)(lp), 16, 0, 0)

// ---------------------------------------------------------------------------
// Weight prep: f32 -> f16, stack Wf/Wg/Wh into one (3C x C), stack biases.
// ---------------------------------------------------------------------------
__global__ void prep_weights(const float* __restrict__ Wf, const float* __restrict__ Wg,
                             const float* __restrict__ Wh, const float* __restrict__ Wc,
                             const float* __restrict__ bf, const float* __restrict__ bg,
                             const float* __restrict__ bh,
                             _Float16* __restrict__ Wfgh, _Float16* __restrict__ WcH,
                             float* __restrict__ bstack) {
    int idx = blockIdx.x * 256 + threadIdx.x;
    if (idx < 3 * M2) {
        const float* s = idx < M2 ? Wf : (idx < 2 * M2 ? Wg : Wh);
        int off = idx & (M2 - 1);
        Wfgh[idx] = (_Float16)s[off];
    } else if (idx < 4 * M2) {
        WcH[idx - 3 * M2] = (_Float16)Wc[idx - 3 * M2];
    } else if (idx < 4 * M2 + 3 * CD) {
        int j = idx - 4 * M2;
        const float* s = j < CD ? bf : (j < 2 * CD ? bg : bh);
        bstack[j] = s[j & (CD - 1)];
    }
}

// ---------------------------------------------------------------------------
// Per-batch transpose: x[b][k][n] (f32) -> xT[z][n][k] (f16)
// ---------------------------------------------------------------------------
__global__ void transpose_x(const float* __restrict__ x, _Float16* __restrict__ xT, int b0) {
    __shared__ float tile[32][33];
    int z = blockIdx.z;
    const float* xb = x + (size_t)(b0 + z) * M2;
    _Float16* xTb = xT + (size_t)z * M2;
    int n0 = blockIdx.x * 32, k0 = blockIdx.y * 32;
    int tx = threadIdx.x, ty = threadIdx.y;  // 32 x 8
#pragma unroll
    for (int i = 0; i < 4; i++)
        tile[ty + i * 8][tx] = xb[(size_t)(k0 + ty + i * 8) * CD + n0 + tx];
    __syncthreads();
#pragma unroll
    for (int i = 0; i < 4; i++)
        xTb[(size_t)(n0 + ty + i * 8) * CD + k0 + tx] = (_Float16)tile[tx][ty + i * 8];
}

// ---------------------------------------------------------------------------
// Row softmax over ST (f32, rows are fixed d, reduce over c) -> attnT (f16)
// ---------------------------------------------------------------------------
__global__ __launch_bounds__(256) void softmax_col(const float* __restrict__ ST,
                                                   _Float16* __restrict__ attnT) {
    int d = blockIdx.x, z = blockIdx.y;
    const float* row = ST + ((size_t)z * CD + d) * CD;
    _Float16* orow = attnT + ((size_t)z * CD + d) * CD;
    int t = threadIdx.x;
    float4v v = *(const float4v*)(row + t * 4);
    float mx = fmaxf(fmaxf(v[0], v[1]), fmaxf(v[2], v[3]));
#pragma unroll
    for (int o = 32; o > 0; o >>= 1) mx = fmaxf(mx, __shfl_xor(mx, o));
    __shared__ float redm[4], reds[4];
    int wave = t >> 6, lane = t & 63;
    if (lane == 0) redm[wave] = mx;
    __syncthreads();
    mx = fmaxf(fmaxf(redm[0], redm[1]), fmaxf(redm[2], redm[3]));
    float e[4];
    float s = 0.f;
#pragma unroll
    for (int i = 0; i < 4; i++) {
        e[i] = __expf(v[i] - mx);
        s += e[i];
    }
#pragma unroll
    for (int o = 32; o > 0; o >>= 1) s += __shfl_xor(s, o);
    if (lane == 0) reds[wave] = s;
    __syncthreads();
    s = reds[0] + reds[1] + reds[2] + reds[3];
    float inv = 1.0f / s;
    half4 ov;
#pragma unroll
    for (int i = 0; i < 4; i++) ov[i] = (_Float16)(e[i] * inv);
    *(half4*)(orow + t * 4) = ov;
}

// ---------------------------------------------------------------------------
// NT GEMM: 3-deep counted-vmcnt pipeline + fragment prefetch (ds_read(t+1)
// hidden under MFMA(t)) + XOR-swizzled LDS + setprio.
// C[m][n] = sum_k A[m][k]*B[n][k], K=1024, BK=32, 32 K-tiles.
// 128x128 tile, 4 waves (2x2), mfma_f32_16x16x32_f16. LDS 3x16KiB = 48 KiB.
//
// Per-iter ledger (4 gload_lds per tile per thread; in-order vmcnt retire):
//   top of t: regs=frags(t); outstanding stages {t+1,t+2}=8.
//   lgkmcnt(0)  -> my frags(t) reads done
//   vmcnt(4)    -> MY tile t+1 loads landed
//   s_barrier   -> ALL waves: frags(t) read-done AND tile t+1 landed
//   STAGE(t+3 -> buf[t%3])       (write-safe by barrier)
//   LOADFRAG(next set <- buf[(t+1)%3])  (read-safe by vmcnt-before-barrier)
//   16x MFMA on current set      (hides ds_read latency)
// Tail: t=29 vmcnt(4), t=30 vmcnt(0), t=31 regs-only.
// Swizzle (involution): stage source col = ((lane&3)^((lane>>3)&3))*8,
// read col = kq ^ (((rl>>1)&3)<<3). Conflicts measured 0.
// ---------------------------------------------------------------------------
enum { EP_F16B = 0, EP_F32 = 1, EP_F16 = 2, EP_FIN = 3 };

#define STAGE(T, B)                                                            \
    GLD16(gA + (size_t)(T) * 32, &As[B][wave * 16][0]);                        \
    GLD16(gA1 + (size_t)(T) * 32, &As[B][64 + wave * 16][0]);                  \
    GLD16(gB + (size_t)(T) * 32, &Bs[B][wave * 16][0]);                        \
    GLD16(gB1 + (size_t)(T) * 32, &Bs[B][64 + wave * 16][0]);

#define LOADFRAG(SET, BUF)                                                     \
    _Pragma("unroll") for (int m = 0; m < 4; m++)                              \
        af##SET[m] = *(const half8*)&As[BUF][wr * 64 + m * 16 + rl][kqa];      \
    _Pragma("unroll") for (int n = 0; n < 4; n++)                              \
        bq##SET[n] = *(const half8*)&Bs[BUF][wc * 64 + n * 16 + rl][kqa];

#define MFMA16(SET)                                                            \
    __builtin_amdgcn_s_setprio(1);                                             \
    _Pragma("unroll") for (int m = 0; m < 4; m++)                              \
        _Pragma("unroll") for (int n = 0; n < 4; n++)                          \
            acc[m][n] = __builtin_amdgcn_mfma_f32_16x16x32_f16(                \
                af##SET[m], bq##SET[n], acc[m][n], 0, 0, 0);                   \
    __builtin_amdgcn_s_setprio(0);

#define KITER(T, CUR, NXT, DOSTAGE, VMSTR, DOLOAD, DOBAR)                      \
    asm volatile("s_waitcnt lgkmcnt(0)" ::: "memory");                         \
    asm volatile("s_waitcnt " VMSTR ::: "memory");                             \
    if (DOBAR) __builtin_amdgcn_s_barrier();                                   \
    if (DOSTAGE) { STAGE((T) + 3, (T) % 3) }                                   \
    __builtin_amdgcn_sched_barrier(0);                                         \
    if (DOLOAD) { LOADFRAG(NXT, ((T) + 1) % 3) }                               \
    MFMA16(CUR)

template <int EPI>
__global__ __launch_bounds__(256) void gemm_nt(
    const _Float16* __restrict__ A, int64_t sA, const _Float16* __restrict__ B, int64_t sB,
    void* __restrict__ Cp, int64_t sC, const float* __restrict__ bias,
    const float* __restrict__ bc, const float* __restrict__ gamma,
    const float* __restrict__ beta, const float* __restrict__ rmean,
    const float* __restrict__ rvar, const float* __restrict__ xres) {
    __shared__ __align__(16) _Float16 As[3][128][32];
    __shared__ __align__(16) _Float16 Bs[3][128][32];
    int z = blockIdx.z;
    const _Float16* Ab = A + (size_t)z * sA;
    const _Float16* Bb = B + (size_t)z * sB;
    int row0 = blockIdx.y * 128, col0 = blockIdx.x * 128;
    int tid = threadIdx.x, lane = tid & 63, wave = tid >> 6;
    int wr = wave >> 1, wc = wave & 1;

    // Staging: wave w covers LDS rows [w*16,+16) (+64 for 2nd issue);
    // lane l -> row + l/4, source col pre-swizzled (LDS dest stays linear).
    const int srow = lane >> 2;
    const int scol = ((lane & 3) ^ ((lane >> 3) & 3)) * 8;
    const _Float16* gA  = Ab + (size_t)(row0 + wave * 16 + srow) * 1024 + scol;
    const _Float16* gA1 = gA + (size_t)64 * 1024;
    const _Float16* gB  = Bb + (size_t)(col0 + wave * 16 + srow) * 1024 + scol;
    const _Float16* gB1 = gB + (size_t)64 * 1024;

    const int rl = lane & 15;
    const int kq = (lane >> 4) * 8;
    const int kqa = kq ^ (((rl >> 1) & 3) << 3);  // read-side swizzle

    float4v acc[4][4] = {};
    half8 af0[4], bq0[4], af1[4], bq1[4];

    // Prologue: fill 3-deep pipeline, pre-read frags(0) into set 0.
    STAGE(0, 0)
    STAGE(1, 1)
    STAGE(2, 2)
    asm volatile("s_waitcnt vmcnt(8)" ::: "memory");
    __builtin_amdgcn_s_barrier();
    __builtin_amdgcn_sched_barrier(0);
    LOADFRAG(0, 0)

#pragma unroll 1
    for (int t = 0; t < 28; t += 2) {
        KITER(t, 0, 1, 1, "vmcnt(4)", 1, 1)
        KITER(t + 1, 1, 0, 1, "vmcnt(4)", 1, 1)
    }
    KITER(28, 0, 1, 1, "vmcnt(4)", 1, 1)   // stages tile 31
    KITER(29, 1, 0, 0, "vmcnt(4)", 1, 1)
    KITER(30, 0, 1, 0, "vmcnt(0)", 1, 1)
    KITER(31, 1, 0, 0, "vmcnt(0)", 0, 0)

    // Epilogue. C/D layout: col = lane&15, row = (lane>>4)*4 + reg  [m89]
#pragma unroll
    for (int m = 0; m < 4; m++) {
#pragma unroll
        for (int r = 0; r < 4; r++) {
            int row = row0 + wr * 64 + m * 16 + ((lane >> 4) << 2) + r;
            float add0 = 0.f, mu = 0.f, invs = 1.f, bet = 0.f;
            if constexpr (EPI == EP_F16B) add0 = bias[row];
            if constexpr (EPI == EP_FIN) {
                add0 = bc[row];
                mu = rmean[row];
                invs = gamma[row] * rsqrtf(rvar[row] + 1e-5f);
                bet = beta[row];
            }
#pragma unroll
            for (int n = 0; n < 4; n++) {
                int col = col0 + wc * 64 + n * 16 + (lane & 15);
                float v = acc[m][n][r];
                if constexpr (EPI == EP_F16B) {
                    ((_Float16*)Cp)[(size_t)z * sC + (size_t)row * 1024 + col] = (_Float16)(v + add0);
                } else if constexpr (EPI == EP_F32) {
                    ((float*)Cp)[(size_t)z * sC + (size_t)row * 1024 + col] = v;
                } else if constexpr (EPI == EP_F16) {
                    ((_Float16*)Cp)[(size_t)z * sC + (size_t)row * 1024 + col] = (_Float16)v;
                } else {
                    v += add0;
                    v = v >= 0.f ? v : 0.01f * v;
                    v = (v - mu) * invs + bet;
                    v += xres[(size_t)z * M2 + (size_t)row * 1024 + col];
                    ((float*)Cp)[(size_t)z * sC + (size_t)row * 1024 + col] = v;
                }
            }
        }
    }
}

// ---------------------------------------------------------------------------
extern "C" void kernel_launch(void* const* d_in, const int* in_sizes, int n_in,
                              void* d_out, int out_size, void* d_ws, size_t ws_size,
                              hipStream_t stream) {
    const float* x = (const float*)d_in[0];
    const float* Wf = (const float*)d_in[1];
    const float* bf = (const float*)d_in[2];
    const float* Wg = (const float*)d_in[3];
    const float* bg = (const float*)d_in[4];
    const float* Wh = (const float*)d_in[5];
    const float* bh = (const float*)d_in[6];
    const float* Wc = (const float*)d_in[7];
    const float* bc = (const float*)d_in[8];
    const float* gamma = (const float*)d_in[9];
    const float* beta = (const float*)d_in[10];
    const float* rmean = (const float*)d_in[11];
    const float* rvar = (const float*)d_in[12];

    // Fixed ws region: Wfgh f16 (6MB) + Wc f16 (2MB) + bias stack
    char* p = (char*)d_ws;
    _Float16* Wfgh = (_Float16*)p;
    p += (size_t)3 * M2 * 2;
    _Float16* WcH = (_Float16*)p;
    p += (size_t)M2 * 2;
    float* bstack = (float*)p;
    p += (size_t)3 * CD * 4;
    size_t fixed = (size_t)(p - (char*)d_ws);
    fixed = (fixed + 255) & ~(size_t)255;

    // Per-batch region: xT f16 (2MB, reused as attnT) + FGH f16 (6MB) +
    // ST f32 (4MB, reused as hfgT f16). 12 MiB per batch.
    size_t perB = (size_t)2 * M2 + (size_t)6 * M2 + (size_t)4 * M2;
    int nb = 16;
    while (nb > 1 && fixed + (size_t)nb * perB > ws_size) nb >>= 1;

    {
        int total = 4 * M2 + 3 * CD;
        prep_weights<<<dim3((total + 255) / 256), dim3(256), 0, stream>>>(
            Wf, Wg, Wh, Wc, bf, bg, bh, Wfgh, WcH, bstack);
    }

    for (int b0 = 0; b0 < 16; b0 += nb) {
        char* q = (char*)d_ws + fixed;
        _Float16* xT = (_Float16*)q;
        _Float16* FGH = (_Float16*)(q + (size_t)nb * 2 * M2);
        float* ST = (float*)(q + (size_t)nb * 8 * M2);
        _Float16* attnT = xT;          // xT dead after GEMM1
        _Float16* hfgT = (_Float16*)ST;  // ST dead after softmax

        // xT[z][n][k] = x[b0+z][k][n]
        transpose_x<<<dim3(32, 32, nb), dim3(32, 8), 0, stream>>>(x, xT, b0);
        // FGH[z] (3072 x 1024) = Wfgh (3072x1024) . xT[z]^T  + bias
        gemm_nt<EP_F16B><<<dim3(8, 24, nb), dim3(256), 0, stream>>>(
            Wfgh, 0, xT, M2, FGH, (int64_t)3 * M2, bstack,
            nullptr, nullptr, nullptr, nullptr, nullptr, nullptr);
        // ST[z][d][c] = sum_n G[d][n] F[c][n]
        gemm_nt<EP_F32><<<dim3(8, 8, nb), dim3(256), 0, stream>>>(
            FGH + M2, (int64_t)3 * M2, FGH, (int64_t)3 * M2, ST, M2,
            nullptr, nullptr, nullptr, nullptr, nullptr, nullptr, nullptr);
        // attnT[z][d][c] = softmax over c of ST[z][d][:]
        softmax_col<<<dim3(1024, nb), dim3(256), 0, stream>>>(ST, attnT);
        // hfgT[z][d][c] = sum_n attnT[d][n] H[c][n]
        gemm_nt<EP_F16><<<dim3(8, 8, nb), dim3(256), 0, stream>>>(
            attnT, M2, FGH + 2 * M2, (int64_t)3 * M2, hfgT, M2,
            nullptr, nullptr, nullptr, nullptr, nullptr, nullptr, nullptr);
        // out[b][o][d] = BN(leaky(Wc . hfgT^T + bc)) + x
        gemm_nt<EP_FIN><<<dim3(8, 8, nb), dim3(256), 0, stream>>>(
            WcH, 0, hfgT, M2, (float*)d_out + (size_t)b0 * M2, M2,
            nullptr, bc, gamma, beta, rmean, rvar, x + (size_t)b0 * M2);
    }
}

// Round 5
// 321.002 us; speedup vs baseline: 1.1545x; 1.1545x over previous
//
#include <hip/hip_runtime.h>
#include <cstdint>
#include <cstddef>

using half8  = __attribute__((ext_vector_type(8))) _Float16;
using half4  = __attribute__((ext_vector_type(4))) _Float16;
using float4v = __attribute__((ext_vector_type(4))) float;

#define CD 1024
#define M2 (1024 * 1024)

// async global->LDS, 16B per lane, wave-uniform LDS base + lane*16 dest
#define GLD16(gp, lp)                                                          \
    __builtin_amdgcn_global_load_lds(                                          \
        (const __attribute__((address_space(1))) void*)(gp),                   \
        (__attribute__((address_space(3))) void*)(lp), 16, 0, 0)

// ---------------------------------------------------------------------------
// Weight prep: f32 -> f16, stack Wf/Wg/Wh into one (3C x C), stack biases.
// ---------------------------------------------------------------------------
__global__ void prep_weights(const float* __restrict__ Wf, const float* __restrict__ Wg,
                             const float* __restrict__ Wh, const float* __restrict__ Wc,
                             const float* __restrict__ bf, const float* __restrict__ bg,
                             const float* __restrict__ bh,
                             _Float16* __restrict__ Wfgh, _Float16* __restrict__ WcH,
                             float* __restrict__ bstack) {
    int idx = blockIdx.x * 256 + threadIdx.x;
    if (idx < 3 * M2) {
        const float* s = idx < M2 ? Wf : (idx < 2 * M2 ? Wg : Wh);
        int off = idx & (M2 - 1);
        Wfgh[idx] = (_Float16)s[off];
    } else if (idx < 4 * M2) {
        WcH[idx - 3 * M2] = (_Float16)Wc[idx - 3 * M2];
    } else if (idx < 4 * M2 + 3 * CD) {
        int j = idx - 4 * M2;
        const float* s = j < CD ? bf : (j < 2 * CD ? bg : bh);
        bstack[j] = s[j & (CD - 1)];
    }
}

// ---------------------------------------------------------------------------
// Per-batch transpose: x[b][k][n] (f32) -> xT[z][n][k] (f16)
// ---------------------------------------------------------------------------
__global__ void transpose_x(const float* __restrict__ x, _Float16* __restrict__ xT, int b0) {
    __shared__ float tile[32][33];
    int z = blockIdx.z;
    const float* xb = x + (size_t)(b0 + z) * M2;
    _Float16* xTb = xT + (size_t)z * M2;
    int n0 = blockIdx.x * 32, k0 = blockIdx.y * 32;
    int tx = threadIdx.x, ty = threadIdx.y;  // 32 x 8
#pragma unroll
    for (int i = 0; i < 4; i++)
        tile[ty + i * 8][tx] = xb[(size_t)(k0 + ty + i * 8) * CD + n0 + tx];
    __syncthreads();
#pragma unroll
    for (int i = 0; i < 4; i++)
        xTb[(size_t)(n0 + ty + i * 8) * CD + k0 + tx] = (_Float16)tile[tx][ty + i * 8];
}

// ---------------------------------------------------------------------------
// Row softmax over ST (f32, rows are fixed d, reduce over c) -> attnT (f16)
// ---------------------------------------------------------------------------
__global__ __launch_bounds__(256) void softmax_col(const float* __restrict__ ST,
                                                   _Float16* __restrict__ attnT) {
    int d = blockIdx.x, z = blockIdx.y;
    const float* row = ST + ((size_t)z * CD + d) * CD;
    _Float16* orow = attnT + ((size_t)z * CD + d) * CD;
    int t = threadIdx.x;
    float4v v = *(const float4v*)(row + t * 4);
    float mx = fmaxf(fmaxf(v[0], v[1]), fmaxf(v[2], v[3]));
#pragma unroll
    for (int o = 32; o > 0; o >>= 1) mx = fmaxf(mx, __shfl_xor(mx, o));
    __shared__ float redm[4], reds[4];
    int wave = t >> 6, lane = t & 63;
    if (lane == 0) redm[wave] = mx;
    __syncthreads();
    mx = fmaxf(fmaxf(redm[0], redm[1]), fmaxf(redm[2], redm[3]));
    float e[4];
    float s = 0.f;
#pragma unroll
    for (int i = 0; i < 4; i++) {
        e[i] = __expf(v[i] - mx);
        s += e[i];
    }
#pragma unroll
    for (int o = 32; o > 0; o >>= 1) s += __shfl_xor(s, o);
    if (lane == 0) reds[wave] = s;
    __syncthreads();
    s = reds[0] + reds[1] + reds[2] + reds[3];
    float inv = 1.0f / s;
    half4 ov;
#pragma unroll
    for (int i = 0; i < 4; i++) ov[i] = (_Float16)(e[i] * inv);
    *(half4*)(orow + t * 4) = ov;
}

// ---------------------------------------------------------------------------
// NT GEMM, 256x256 phase-interleaved template (per m194-m201 geometry):
// C[m][n] = sum_k A[m][k]*B[n][k], K=1024, BK=32, 32 K-tiles.
// 8 waves (2Mx4N), per-wave output 128x64 (acc[8][4]), 16x16x32 f16 MFMA.
// LDS: 4 K-tile buffers x (A 256x32 + B 256x32) f16 = 128 KiB; 1 block/CU.
//
// Per K-tile t: 2 phases of 16 MFMA:
//   PHASE_A: ds_read a[0..3]+b[0..3] (12xb128); stage Apan(t+3); barrier;
//            lgkm(0); MFMA m0-3 x n0-3; barrier.
//   PHASE_B: ds_read a[4..7] (4xb128); stage Bpan(t+4); barrier; lgkm(0);
//            MFMA m4-7 x n0-3; vmcnt(10); barrier.
// Ledger (2 loads/half-stage, in-order retire): stage order
//   ...Apan(t+3)@A(t), Bpan(t+4)@B(t)...; at B(t) checkpoint the loads after
//   Apan(t+1) are 5 half-stages = vmcnt(10) -> tile t+1 fully landed before
//   its reads at A(t+1). Prologue A0,B0,A1,B1,A2,B2,B3 -> vmcnt(10).
//   Tail: vmcnt(8)@B(28), (4)@B(29), (0)@B(30).
// Write-safety: Apan(s+3) overwrites A-panel last read at B(s-1) [barrier2
//   separates]; Bpan(s+4) overwrites B-panel last read at A(s) [barrier2].
// Read-safety: vmcnt precedes barrier2 (publishes all waves' stages).
// Swizzle (involution on 8-elem groups): stage source col =
//   ((lane&3)^((lane>>2)&3))*8 with linear LDS dest; read col =
//   ((lane>>4)*8) ^ ((lane&3)<<3). Conflict-free (measured 0 at r3).
// ---------------------------------------------------------------------------
enum { EP_F16B = 0, EP_F32 = 1, EP_F16 = 2, EP_FIN = 3 };

#define STAGE_A(T, BUF)                                                        \
    GLD16(gA0 + (size_t)(T) * 32, &As[BUF][wv * 16][0]);                       \
    GLD16(gA1 + (size_t)(T) * 32, &As[BUF][128 + wv * 16][0]);
#define STAGE_B(T, BUF)                                                        \
    GLD16(gB0 + (size_t)(T) * 32, &Bs[BUF][wv * 16][0]);                       \
    GLD16(gB1 + (size_t)(T) * 32, &Bs[BUF][128 + wv * 16][0]);

#define MFMA_HALF(M0)                                                          \
    __builtin_amdgcn_s_setprio(1);                                             \
    _Pragma("unroll") for (int m = M0; m < (M0) + 4; m++)                      \
        _Pragma("unroll") for (int n = 0; n < 4; n++)                          \
            acc[m][n] = __builtin_amdgcn_mfma_f32_16x16x32_f16(                \
                a[m], b[n], acc[m][n], 0, 0, 0);                               \
    __builtin_amdgcn_s_setprio(0);

#define PHASE_A(BUF, SA, SAT, SAB)                                             \
    {                                                                          \
        _Pragma("unroll") for (int m = 0; m < 4; m++)                          \
            a[m] = *(const half8*)&As[BUF][wr * 128 + m * 16 + rl][kqa];       \
        _Pragma("unroll") for (int n = 0; n < 4; n++)                          \
            b[n] = *(const half8*)&Bs[BUF][wc * 64 + n * 16 + rl][kqa];        \
        if (SA) { STAGE_A(SAT, SAB) }                                          \
        __builtin_amdgcn_s_barrier();                                          \
        asm volatile("s_waitcnt lgkmcnt(0)" ::: "memory");                     \
        __builtin_amdgcn_sched_barrier(0);                                     \
        MFMA_HALF(0)                                                           \
        __builtin_amdgcn_s_barrier();                                          \
    }

#define PHASE_B(BUF, SB, SBT, SBB, VM, VMS, EBAR)                              \
    {                                                                          \
        _Pragma("unroll") for (int m = 4; m < 8; m++)                          \
            a[m] = *(const half8*)&As[BUF][wr * 128 + m * 16 + rl][kqa];       \
        if (SB) { STAGE_B(SBT, SBB) }                                          \
        __builtin_amdgcn_s_barrier();                                          \
        asm volatile("s_waitcnt lgkmcnt(0)" ::: "memory");                     \
        __builtin_amdgcn_sched_barrier(0);                                     \
        MFMA_HALF(4)                                                           \
        if (VM) {                                                              \
            asm volatile("s_waitcnt " VMS ::: "memory");                       \
            __builtin_amdgcn_sched_barrier(0);                                 \
        }                                                                      \
        if (EBAR) __builtin_amdgcn_s_barrier();                                \
    }

template <int EPI>
__global__ __launch_bounds__(512, 2) void gemm_nt(
    const _Float16* __restrict__ A, int64_t sA, const _Float16* __restrict__ B, int64_t sB,
    void* __restrict__ Cp, int64_t sC, const float* __restrict__ bias,
    const float* __restrict__ bc, const float* __restrict__ gamma,
    const float* __restrict__ beta, const float* __restrict__ rmean,
    const float* __restrict__ rvar, const float* __restrict__ xres) {
    __shared__ __align__(16) _Float16 As[4][256][32];
    __shared__ __align__(16) _Float16 Bs[4][256][32];
    int z = blockIdx.z;
    const _Float16* Ab = A + (size_t)z * sA;
    const _Float16* Bb = B + (size_t)z * sB;
    int row0 = blockIdx.y * 256, col0 = blockIdx.x * 256;
    int tid = threadIdx.x, lane = tid & 63, wv = tid >> 6;
    int wr = wv >> 2, wc = wv & 3;

    // Staging: issue i covers rows [i*128 + wv*16, +16); lane l -> row + l/4,
    // source col pre-swizzled (LDS dest stays linear).
    const int srow = wv * 16 + (lane >> 2);
    const int scol = ((lane & 3) ^ ((lane >> 2) & 3)) * 8;
    const _Float16* gA0 = Ab + (size_t)(row0 + srow) * 1024 + scol;
    const _Float16* gA1 = gA0 + (size_t)128 * 1024;
    const _Float16* gB0 = Bb + (size_t)(col0 + srow) * 1024 + scol;
    const _Float16* gB1 = gB0 + (size_t)128 * 1024;

    const int rl = lane & 15;
    const int kqa = ((lane >> 4) * 8) ^ ((lane & 3) << 3);  // read-side swizzle

    float4v acc[8][4] = {};
    half8 a[8], b[4];

    // Prologue: A0,B0,A1,B1,A2,B2,B3 (Apan3 staged at phase A(0)).
    STAGE_A(0, 0) STAGE_B(0, 0) STAGE_A(1, 1) STAGE_B(1, 1)
    STAGE_A(2, 2) STAGE_B(2, 2) STAGE_B(3, 3)
    asm volatile("s_waitcnt vmcnt(10)" ::: "memory");
    __builtin_amdgcn_sched_barrier(0);
    __builtin_amdgcn_s_barrier();

#pragma unroll 1
    for (int tq = 0; tq < 7; ++tq) {  // tiles t..t+3, t=4tq, all stages on
        int t = tq * 4;
        PHASE_A(0, 1, t + 3, 3) PHASE_B(0, 1, t + 4, 0, 1, "vmcnt(10)", 1)
        PHASE_A(1, 1, t + 4, 0) PHASE_B(1, 1, t + 5, 1, 1, "vmcnt(10)", 1)
        PHASE_A(2, 1, t + 5, 1) PHASE_B(2, 1, t + 6, 2, 1, "vmcnt(10)", 1)
        PHASE_A(3, 1, t + 6, 2) PHASE_B(3, 1, t + 7, 3, 1, "vmcnt(10)", 1)
    }
    // Tiles 28..31 (tail; last A-stage = Apan31 at A(28)).
    PHASE_A(0, 1, 31, 3) PHASE_B(0, 0, 0, 0, 1, "vmcnt(8)", 1)
    PHASE_A(1, 0, 0, 0)  PHASE_B(1, 0, 0, 0, 1, "vmcnt(4)", 1)
    PHASE_A(2, 0, 0, 0)  PHASE_B(2, 0, 0, 0, 1, "vmcnt(0)", 1)
    PHASE_A(3, 0, 0, 0)  PHASE_B(3, 0, 0, 0, 0, "", 0)

    // Epilogue. C/D layout: col = lane&15, row = (lane>>4)*4 + reg  [m89]
#pragma unroll
    for (int m = 0; m < 8; m++) {
#pragma unroll
        for (int r = 0; r < 4; r++) {
            int row = row0 + wr * 128 + m * 16 + ((lane >> 4) << 2) + r;
            float add0 = 0.f, mu = 0.f, invs = 1.f, bet = 0.f;
            if constexpr (EPI == EP_F16B) add0 = bias[row];
            if constexpr (EPI == EP_FIN) {
                add0 = bc[row];
                mu = rmean[row];
                invs = gamma[row] * rsqrtf(rvar[row] + 1e-5f);
                bet = beta[row];
            }
#pragma unroll
            for (int n = 0; n < 4; n++) {
                int col = col0 + wc * 64 + n * 16 + (lane & 15);
                float v = acc[m][n][r];
                if constexpr (EPI == EP_F16B) {
                    ((_Float16*)Cp)[(size_t)z * sC + (size_t)row * 1024 + col] = (_Float16)(v + add0);
                } else if constexpr (EPI == EP_F32) {
                    ((float*)Cp)[(size_t)z * sC + (size_t)row * 1024 + col] = v;
                } else if constexpr (EPI == EP_F16) {
                    ((_Float16*)Cp)[(size_t)z * sC + (size_t)row * 1024 + col] = (_Float16)v;
                } else {
                    v += add0;
                    v = v >= 0.f ? v : 0.01f * v;
                    v = (v - mu) * invs + bet;
                    v += xres[(size_t)z * M2 + (size_t)row * 1024 + col];
                    ((float*)Cp)[(size_t)z * sC + (size_t)row * 1024 + col] = v;
                }
            }
        }
    }
}

// ---------------------------------------------------------------------------
extern "C" void kernel_launch(void* const* d_in, const int* in_sizes, int n_in,
                              void* d_out, int out_size, void* d_ws, size_t ws_size,
                              hipStream_t stream) {
    const float* x = (const float*)d_in[0];
    const float* Wf = (const float*)d_in[1];
    const float* bf = (const float*)d_in[2];
    const float* Wg = (const float*)d_in[3];
    const float* bg = (const float*)d_in[4];
    const float* Wh = (const float*)d_in[5];
    const float* bh = (const float*)d_in[6];
    const float* Wc = (const float*)d_in[7];
    const float* bc = (const float*)d_in[8];
    const float* gamma = (const float*)d_in[9];
    const float* beta = (const float*)d_in[10];
    const float* rmean = (const float*)d_in[11];
    const float* rvar = (const float*)d_in[12];

    // Fixed ws region: Wfgh f16 (6MB) + Wc f16 (2MB) + bias stack
    char* p = (char*)d_ws;
    _Float16* Wfgh = (_Float16*)p;
    p += (size_t)3 * M2 * 2;
    _Float16* WcH = (_Float16*)p;
    p += (size_t)M2 * 2;
    float* bstack = (float*)p;
    p += (size_t)3 * CD * 4;
    size_t fixed = (size_t)(p - (char*)d_ws);
    fixed = (fixed + 255) & ~(size_t)255;

    // Per-batch region: xT f16 (2MB, reused as attnT) + FGH f16 (6MB) +
    // ST f32 (4MB, reused as hfgT f16). 12 MiB per batch.
    size_t perB = (size_t)2 * M2 + (size_t)6 * M2 + (size_t)4 * M2;
    int nb = 16;
    while (nb > 1 && fixed + (size_t)nb * perB > ws_size) nb >>= 1;

    {
        int total = 4 * M2 + 3 * CD;
        prep_weights<<<dim3((total + 255) / 256), dim3(256), 0, stream>>>(
            Wf, Wg, Wh, Wc, bf, bg, bh, Wfgh, WcH, bstack);
    }

    for (int b0 = 0; b0 < 16; b0 += nb) {
        char* q = (char*)d_ws + fixed;
        _Float16* xT = (_Float16*)q;
        _Float16* FGH = (_Float16*)(q + (size_t)nb * 2 * M2);
        float* ST = (float*)(q + (size_t)nb * 8 * M2);
        _Float16* attnT = xT;          // xT dead after GEMM1
        _Float16* hfgT = (_Float16*)ST;  // ST dead after softmax

        // xT[z][n][k] = x[b0+z][k][n]
        transpose_x<<<dim3(32, 32, nb), dim3(32, 8), 0, stream>>>(x, xT, b0);
        // FGH[z] (3072 x 1024) = Wfgh (3072x1024) . xT[z]^T  + bias
        gemm_nt<EP_F16B><<<dim3(4, 12, nb), dim3(512), 0, stream>>>(
            Wfgh, 0, xT, M2, FGH, (int64_t)3 * M2, bstack,
            nullptr, nullptr, nullptr, nullptr, nullptr, nullptr);
        // ST[z][d][c] = sum_n G[d][n] F[c][n]
        gemm_nt<EP_F32><<<dim3(4, 4, nb), dim3(512), 0, stream>>>(
            FGH + M2, (int64_t)3 * M2, FGH, (int64_t)3 * M2, ST, M2,
            nullptr, nullptr, nullptr, nullptr, nullptr, nullptr, nullptr);
        // attnT[z][d][c] = softmax over c of ST[z][d][:]
        softmax_col<<<dim3(1024, nb), dim3(256), 0, stream>>>(ST, attnT);
        // hfgT[z][d][c] = sum_n attnT[d][n] H[c][n]
        gemm_nt<EP_F16><<<dim3(4, 4, nb), dim3(512), 0, stream>>>(
            attnT, M2, FGH + 2 * M2, (int64_t)3 * M2, hfgT, M2,
            nullptr, nullptr, nullptr, nullptr, nullptr, nullptr, nullptr);
        // out[b][o][d] = BN(leaky(Wc . hfgT^T + bc)) + x
        gemm_nt<EP_FIN><<<dim3(4, 4, nb), dim3(512), 0, stream>>>(
            WcH, 0, hfgT, M2, (float*)d_out + (size_t)b0 * M2, M2,
            nullptr, bc, gamma, beta, rmean, rvar, x + (size_t)b0 * M2);
    }
}

// Round 6
// 311.777 us; speedup vs baseline: 1.1886x; 1.0296x over previous
//
#include <hip/hip_runtime.h>
#include <cstdint>
#include <cstddef>

using half8  = __attribute__((ext_vector_type(8))) _Float16;
using half4  = __attribute__((ext_vector_type(4))) _Float16;
using float4v = __attribute__((ext_vector_type(4))) float;

#define CD 1024
#define M2 (1024 * 1024)

// async global->LDS, 16B per lane, wave-uniform LDS base + lane*16 dest
#define GLD16(gp, lp)                                                          \
    __builtin_amdgcn_global_load_lds(                                          \
        (const __attribute__((address_space(1))) void*)(gp),                   \
        (__attribute__((address_space(3))) void*)(lp), 16, 0, 0)

// ---------------------------------------------------------------------------
// Weight prep: f32 -> f16, stack Wf/Wg/Wh into one (3C x C), stack biases.
// ---------------------------------------------------------------------------
__global__ void prep_weights(const float* __restrict__ Wf, const float* __restrict__ Wg,
                             const float* __restrict__ Wh, const float* __restrict__ Wc,
                             const float* __restrict__ bf, const float* __restrict__ bg,
                             const float* __restrict__ bh,
                             _Float16* __restrict__ Wfgh, _Float16* __restrict__ WcH,
                             float* __restrict__ bstack) {
    int idx = blockIdx.x * 256 + threadIdx.x;
    if (idx < 3 * M2) {
        const float* s = idx < M2 ? Wf : (idx < 2 * M2 ? Wg : Wh);
        int off = idx & (M2 - 1);
        Wfgh[idx] = (_Float16)s[off];
    } else if (idx < 4 * M2) {
        WcH[idx - 3 * M2] = (_Float16)Wc[idx - 3 * M2];
    } else if (idx < 4 * M2 + 3 * CD) {
        int j = idx - 4 * M2;
        const float* s = j < CD ? bf : (j < 2 * CD ? bg : bh);
        bstack[j] = s[j & (CD - 1)];
    }
}

// ---------------------------------------------------------------------------
// Per-batch transpose: x[b][k][n] (f32) -> xT[z][n][k] (f16)
// ---------------------------------------------------------------------------
__global__ void transpose_x(const float* __restrict__ x, _Float16* __restrict__ xT, int b0) {
    __shared__ float tile[32][33];
    int z = blockIdx.z;
    const float* xb = x + (size_t)(b0 + z) * M2;
    _Float16* xTb = xT + (size_t)z * M2;
    int n0 = blockIdx.x * 32, k0 = blockIdx.y * 32;
    int tx = threadIdx.x, ty = threadIdx.y;  // 32 x 8
#pragma unroll
    for (int i = 0; i < 4; i++)
        tile[ty + i * 8][tx] = xb[(size_t)(k0 + ty + i * 8) * CD + n0 + tx];
    __syncthreads();
#pragma unroll
    for (int i = 0; i < 4; i++)
        xTb[(size_t)(n0 + ty + i * 8) * CD + k0 + tx] = (_Float16)tile[tx][ty + i * 8];
}

// ---------------------------------------------------------------------------
// Row softmax over ST (f32, rows are fixed d, reduce over c) -> attnT (f16)
// ---------------------------------------------------------------------------
__global__ __launch_bounds__(256) void softmax_col(const float* __restrict__ ST,
                                                   _Float16* __restrict__ attnT) {
    int d = blockIdx.x, z = blockIdx.y;
    const float* row = ST + ((size_t)z * CD + d) * CD;
    _Float16* orow = attnT + ((size_t)z * CD + d) * CD;
    int t = threadIdx.x;
    float4v v = *(const float4v*)(row + t * 4);
    float mx = fmaxf(fmaxf(v[0], v[1]), fmaxf(v[2], v[3]));
#pragma unroll
    for (int o = 32; o > 0; o >>= 1) mx = fmaxf(mx, __shfl_xor(mx, o));
    __shared__ float redm[4], reds[4];
    int wave = t >> 6, lane = t & 63;
    if (lane == 0) redm[wave] = mx;
    __syncthreads();
    mx = fmaxf(fmaxf(redm[0], redm[1]), fmaxf(redm[2], redm[3]));
    float e[4];
    float s = 0.f;
#pragma unroll
    for (int i = 0; i < 4; i++) {
        e[i] = __expf(v[i] - mx);
        s += e[i];
    }
#pragma unroll
    for (int o = 32; o > 0; o >>= 1) s += __shfl_xor(s, o);
    if (lane == 0) reds[wave] = s;
    __syncthreads();
    s = reds[0] + reds[1] + reds[2] + reds[3];
    float inv = 1.0f / s;
    half4 ov;
#pragma unroll
    for (int i = 0; i < 4; i++) ov[i] = (_Float16)(e[i] * inv);
    *(half4*)(orow + t * 4) = ov;
}

// ---------------------------------------------------------------------------
// NT GEMM, 256x256 phase-interleaved template (per m194-m201 geometry):
// C[m][n] = sum_k A[m][k]*B[n][k], K=1024, BK=32, 32 K-tiles.
// 8 waves (2Mx4N), per-wave output 128x64 (acc[8][4]), 16x16x32 f16 MFMA.
// LDS: 4 K-tile buffers x (A 256x32 + B 256x32) f16 = 128 KiB; 1 block/CU.
//
// Per K-tile t: 2 phases of 16 MFMA:
//   PHASE_A: ds_read a[0..3]+b[0..3] (8xb128); stage Apan(t+3); barrier;
//            lgkm(0); MFMA m0-3 x n0-3; barrier.
//   PHASE_B: ds_read a[4..7] (4xb128); stage Bpan(t+4); barrier; lgkm(0);
//            MFMA m4-7 x n0-3; vmcnt(10); barrier.
// Ledger (2 loads/half-stage, in-order retire): stage order
//   ...Apan(t+3)@A(t), Bpan(t+4)@B(t)...; at B(t) checkpoint the loads after
//   Apan(t+1) are 5 half-stages = vmcnt(10) -> tile t+1 fully landed before
//   its reads at A(t+1). Prologue A0,B0,A1,B1,A2,B2,B3 -> vmcnt(10).
//   Tail: vmcnt(8)@B(28), (4)@B(29), (0)@B(30).
// Write-safety: Apan(s+3) overwrites A-panel last read at B(s-1) [barrier2
//   separates]; Bpan(s+4) overwrites B-panel last read at A(s) [barrier2].
// Read-safety: vmcnt precedes barrier2 (publishes all waves' stages).
// Swizzle (r3-verified conflict-free pair; LDS[r][c8]=global[c8^(((r&15)>>1)&3)]):
//   stage source col = ((lane&3) ^ ((lane>>3)&3))*8, linear LDS dest;
//   read col = kq ^ (((rl>>1)&3)<<3)  [all frag-read rows have row&15==rl].
//   Lanes 0-7 of each half cover all 32 banks; 8-15 alias 2-way (free, m136).
// ---------------------------------------------------------------------------
enum { EP_F16B = 0, EP_F32 = 1, EP_F16 = 2, EP_FIN = 3 };

#define STAGE_A(T, BUF)                                                        \
    GLD16(gA0 + (size_t)(T) * 32, &As[BUF][wv * 16][0]);                       \
    GLD16(gA1 + (size_t)(T) * 32, &As[BUF][128 + wv * 16][0]);
#define STAGE_B(T, BUF)                                                        \
    GLD16(gB0 + (size_t)(T) * 32, &Bs[BUF][wv * 16][0]);                       \
    GLD16(gB1 + (size_t)(T) * 32, &Bs[BUF][128 + wv * 16][0]);

#define MFMA_HALF(M0)                                                          \
    __builtin_amdgcn_s_setprio(1);                                             \
    _Pragma("unroll") for (int m = M0; m < (M0) + 4; m++)                      \
        _Pragma("unroll") for (int n = 0; n < 4; n++)                          \
            acc[m][n] = __builtin_amdgcn_mfma_f32_16x16x32_f16(                \
                a[m], b[n], acc[m][n], 0, 0, 0);                               \
    __builtin_amdgcn_s_setprio(0);

#define PHASE_A(BUF, SA, SAT, SAB)                                             \
    {                                                                          \
        _Pragma("unroll") for (int m = 0; m < 4; m++)                          \
            a[m] = *(const half8*)&As[BUF][wr * 128 + m * 16 + rl][kqa];       \
        _Pragma("unroll") for (int n = 0; n < 4; n++)                          \
            b[n] = *(const half8*)&Bs[BUF][wc * 64 + n * 16 + rl][kqa];        \
        if (SA) { STAGE_A(SAT, SAB) }                                          \
        __builtin_amdgcn_s_barrier();                                          \
        asm volatile("s_waitcnt lgkmcnt(0)" ::: "memory");                     \
        __builtin_amdgcn_sched_barrier(0);                                     \
        MFMA_HALF(0)                                                           \
        __builtin_amdgcn_s_barrier();                                          \
    }

#define PHASE_B(BUF, SB, SBT, SBB, VM, VMS, EBAR)                              \
    {                                                                          \
        _Pragma("unroll") for (int m = 4; m < 8; m++)                          \
            a[m] = *(const half8*)&As[BUF][wr * 128 + m * 16 + rl][kqa];       \
        if (SB) { STAGE_B(SBT, SBB) }                                          \
        __builtin_amdgcn_s_barrier();                                          \
        asm volatile("s_waitcnt lgkmcnt(0)" ::: "memory");                     \
        __builtin_amdgcn_sched_barrier(0);                                     \
        MFMA_HALF(4)                                                           \
        if (VM) {                                                              \
            asm volatile("s_waitcnt " VMS ::: "memory");                       \
            __builtin_amdgcn_sched_barrier(0);                                 \
        }                                                                      \
        if (EBAR) __builtin_amdgcn_s_barrier();                                \
    }

template <int EPI>
__global__ __launch_bounds__(512, 2) void gemm_nt(
    const _Float16* __restrict__ A, int64_t sA, const _Float16* __restrict__ B, int64_t sB,
    void* __restrict__ Cp, int64_t sC, const float* __restrict__ bias,
    const float* __restrict__ bc, const float* __restrict__ gamma,
    const float* __restrict__ beta, const float* __restrict__ rmean,
    const float* __restrict__ rvar, const float* __restrict__ xres) {
    __shared__ __align__(16) _Float16 As[4][256][32];
    __shared__ __align__(16) _Float16 Bs[4][256][32];
    int z = blockIdx.z;
    const _Float16* Ab = A + (size_t)z * sA;
    const _Float16* Bb = B + (size_t)z * sB;
    int row0 = blockIdx.y * 256, col0 = blockIdx.x * 256;
    int tid = threadIdx.x, lane = tid & 63, wv = tid >> 6;
    int wr = wv >> 2, wc = wv & 3;

    // Staging: issue i covers rows [i*128 + wv*16, +16); lane l -> row + l/4,
    // source col pre-swizzled (LDS dest stays linear).
    const int srow = wv * 16 + (lane >> 2);
    const int scol = ((lane & 3) ^ ((lane >> 3) & 3)) * 8;
    const _Float16* gA0 = Ab + (size_t)(row0 + srow) * 1024 + scol;
    const _Float16* gA1 = gA0 + (size_t)128 * 1024;
    const _Float16* gB0 = Bb + (size_t)(col0 + srow) * 1024 + scol;
    const _Float16* gB1 = gB0 + (size_t)128 * 1024;

    const int rl = lane & 15;
    const int kq = (lane >> 4) * 8;
    const int kqa = kq ^ (((rl >> 1) & 3) << 3);  // read-side swizzle

    float4v acc[8][4] = {};
    half8 a[8], b[4];

    // Prologue: A0,B0,A1,B1,A2,B2,B3 (Apan3 staged at phase A(0)).
    STAGE_A(0, 0) STAGE_B(0, 0) STAGE_A(1, 1) STAGE_B(1, 1)
    STAGE_A(2, 2) STAGE_B(2, 2) STAGE_B(3, 3)
    asm volatile("s_waitcnt vmcnt(10)" ::: "memory");
    __builtin_amdgcn_sched_barrier(0);
    __builtin_amdgcn_s_barrier();

#pragma unroll 1
    for (int tq = 0; tq < 7; ++tq) {  // tiles t..t+3, t=4tq, all stages on
        int t = tq * 4;
        PHASE_A(0, 1, t + 3, 3) PHASE_B(0, 1, t + 4, 0, 1, "vmcnt(10)", 1)
        PHASE_A(1, 1, t + 4, 0) PHASE_B(1, 1, t + 5, 1, 1, "vmcnt(10)", 1)
        PHASE_A(2, 1, t + 5, 1) PHASE_B(2, 1, t + 6, 2, 1, "vmcnt(10)", 1)
        PHASE_A(3, 1, t + 6, 2) PHASE_B(3, 1, t + 7, 3, 1, "vmcnt(10)", 1)
    }
    // Tiles 28..31 (tail; last A-stage = Apan31 at A(28)).
    PHASE_A(0, 1, 31, 3) PHASE_B(0, 0, 0, 0, 1, "vmcnt(8)", 1)
    PHASE_A(1, 0, 0, 0)  PHASE_B(1, 0, 0, 0, 1, "vmcnt(4)", 1)
    PHASE_A(2, 0, 0, 0)  PHASE_B(2, 0, 0, 0, 1, "vmcnt(0)", 1)
    PHASE_A(3, 0, 0, 0)  PHASE_B(3, 0, 0, 0, 0, "", 0)

    // Epilogue. C/D layout: col = lane&15, row = (lane>>4)*4 + reg  [m89]
#pragma unroll
    for (int m = 0; m < 8; m++) {
#pragma unroll
        for (int r = 0; r < 4; r++) {
            int row = row0 + wr * 128 + m * 16 + ((lane >> 4) << 2) + r;
            float add0 = 0.f, mu = 0.f, invs = 1.f, bet = 0.f;
            if constexpr (EPI == EP_F16B) add0 = bias[row];
            if constexpr (EPI == EP_FIN) {
                add0 = bc[row];
                mu = rmean[row];
                invs = gamma[row] * rsqrtf(rvar[row] + 1e-5f);
                bet = beta[row];
            }
#pragma unroll
            for (int n = 0; n < 4; n++) {
                int col = col0 + wc * 64 + n * 16 + (lane & 15);
                float v = acc[m][n][r];
                if constexpr (EPI == EP_F16B) {
                    ((_Float16*)Cp)[(size_t)z * sC + (size_t)row * 1024 + col] = (_Float16)(v + add0);
                } else if constexpr (EPI == EP_F32) {
                    ((float*)Cp)[(size_t)z * sC + (size_t)row * 1024 + col] = v;
                } else if constexpr (EPI == EP_F16) {
                    ((_Float16*)Cp)[(size_t)z * sC + (size_t)row * 1024 + col] = (_Float16)v;
                } else {
                    v += add0;
                    v = v >= 0.f ? v : 0.01f * v;
                    v = (v - mu) * invs + bet;
                    v += xres[(size_t)z * M2 + (size_t)row * 1024 + col];
                    ((float*)Cp)[(size_t)z * sC + (size_t)row * 1024 + col] = v;
                }
            }
        }
    }
}

// ---------------------------------------------------------------------------
extern "C" void kernel_launch(void* const* d_in, const int* in_sizes, int n_in,
                              void* d_out, int out_size, void* d_ws, size_t ws_size,
                              hipStream_t stream) {
    const float* x = (const float*)d_in[0];
    const float* Wf = (const float*)d_in[1];
    const float* bf = (const float*)d_in[2];
    const float* Wg = (const float*)d_in[3];
    const float* bg = (const float*)d_in[4];
    const float* Wh = (const float*)d_in[5];
    const float* bh = (const float*)d_in[6];
    const float* Wc = (const float*)d_in[7];
    const float* bc = (const float*)d_in[8];
    const float* gamma = (const float*)d_in[9];
    const float* beta = (const float*)d_in[10];
    const float* rmean = (const float*)d_in[11];
    const float* rvar = (const float*)d_in[12];

    // Fixed ws region: Wfgh f16 (6MB) + Wc f16 (2MB) + bias stack
    char* p = (char*)d_ws;
    _Float16* Wfgh = (_Float16*)p;
    p += (size_t)3 * M2 * 2;
    _Float16* WcH = (_Float16*)p;
    p += (size_t)M2 * 2;
    float* bstack = (float*)p;
    p += (size_t)3 * CD * 4;
    size_t fixed = (size_t)(p - (char*)d_ws);
    fixed = (fixed + 255) & ~(size_t)255;

    // Per-batch region: xT f16 (2MB, reused as attnT) + FGH f16 (6MB) +
    // ST f32 (4MB, reused as hfgT f16). 12 MiB per batch.
    size_t perB = (size_t)2 * M2 + (size_t)6 * M2 + (size_t)4 * M2;
    int nb = 16;
    while (nb > 1 && fixed + (size_t)nb * perB > ws_size) nb >>= 1;

    {
        int total = 4 * M2 + 3 * CD;
        prep_weights<<<dim3((total + 255) / 256), dim3(256), 0, stream>>>(
            Wf, Wg, Wh, Wc, bf, bg, bh, Wfgh, WcH, bstack);
    }

    for (int b0 = 0; b0 < 16; b0 += nb) {
        char* q = (char*)d_ws + fixed;
        _Float16* xT = (_Float16*)q;
        _Float16* FGH = (_Float16*)(q + (size_t)nb * 2 * M2);
        float* ST = (float*)(q + (size_t)nb * 8 * M2);
        _Float16* attnT = xT;          // xT dead after GEMM1
        _Float16* hfgT = (_Float16*)ST;  // ST dead after softmax

        // xT[z][n][k] = x[b0+z][k][n]
        transpose_x<<<dim3(32, 32, nb), dim3(32, 8), 0, stream>>>(x, xT, b0);
        // FGH[z] (3072 x 1024) = Wfgh (3072x1024) . xT[z]^T  + bias
        gemm_nt<EP_F16B><<<dim3(4, 12, nb), dim3(512), 0, stream>>>(
            Wfgh, 0, xT, M2, FGH, (int64_t)3 * M2, bstack,
            nullptr, nullptr, nullptr, nullptr, nullptr, nullptr);
        // ST[z][d][c] = sum_n G[d][n] F[c][n]
        gemm_nt<EP_F32><<<dim3(4, 4, nb), dim3(512), 0, stream>>>(
            FGH + M2, (int64_t)3 * M2, FGH, (int64_t)3 * M2, ST, M2,
            nullptr, nullptr, nullptr, nullptr, nullptr, nullptr, nullptr);
        // attnT[z][d][c] = softmax over c of ST[z][d][:]
        softmax_col<<<dim3(1024, nb), dim3(256), 0, stream>>>(ST, attnT);
        // hfgT[z][d][c] = sum_n attnT[d][n] H[c][n]
        gemm_nt<EP_F16><<<dim3(4, 4, nb), dim3(512), 0, stream>>>(
            attnT, M2, FGH + 2 * M2, (int64_t)3 * M2, hfgT, M2,
            nullptr, nullptr, nullptr, nullptr, nullptr, nullptr, nullptr);
        // out[b][o][d] = BN(leaky(Wc . hfgT^T + bc)) + x
        gemm_nt<EP_FIN><<<dim3(4, 4, nb), dim3(512), 0, stream>>>(
            WcH, 0, hfgT, M2, (float*)d_out + (size_t)b0 * M2, M2,
            nullptr, bc, gamma, beta, rmean, rvar, x + (size_t)b0 * M2);
    }
}

// Round 7
// 301.334 us; speedup vs baseline: 1.2298x; 1.0347x over previous
//
#include <hip/hip_runtime.h>
#include <cstdint>
#include <cstddef>

using half8  = __attribute__((ext_vector_type(8))) _Float16;
using half4  = __attribute__((ext_vector_type(4))) _Float16;
using float4v = __attribute__((ext_vector_type(4))) float;

#define CD 1024
#define M2 (1024 * 1024)

// async global->LDS, 16B per lane, wave-uniform LDS base + lane*16 dest
#define GLD16(gp, lp)                                                          \
    __builtin_amdgcn_global_load_lds(                                          \
        (const __attribute__((address_space(1))) void*)(gp),                   \
        (__attribute__((address_space(3))) void*)(lp), 16, 0, 0)

// ---------------------------------------------------------------------------
// Weight prep: f32 -> f16, stack Wf/Wg/Wh into one (3C x C), stack biases.
// ---------------------------------------------------------------------------
__global__ void prep_weights(const float* __restrict__ Wf, const float* __restrict__ Wg,
                             const float* __restrict__ Wh, const float* __restrict__ Wc,
                             const float* __restrict__ bf, const float* __restrict__ bg,
                             const float* __restrict__ bh,
                             _Float16* __restrict__ Wfgh, _Float16* __restrict__ WcH,
                             float* __restrict__ bstack) {
    int idx = blockIdx.x * 256 + threadIdx.x;
    if (idx < 3 * M2) {
        const float* s = idx < M2 ? Wf : (idx < 2 * M2 ? Wg : Wh);
        int off = idx & (M2 - 1);
        Wfgh[idx] = (_Float16)s[off];
    } else if (idx < 4 * M2) {
        WcH[idx - 3 * M2] = (_Float16)Wc[idx - 3 * M2];
    } else if (idx < 4 * M2 + 3 * CD) {
        int j = idx - 4 * M2;
        const float* s = j < CD ? bf : (j < 2 * CD ? bg : bh);
        bstack[j] = s[j & (CD - 1)];
    }
}

// ---------------------------------------------------------------------------
// Per-batch transpose: x[b][k][n] (f32) -> xT[z][n][k] (f16)
// ---------------------------------------------------------------------------
__global__ void transpose_x(const float* __restrict__ x, _Float16* __restrict__ xT, int b0) {
    __shared__ float tile[32][33];
    int z = blockIdx.z;
    const float* xb = x + (size_t)(b0 + z) * M2;
    _Float16* xTb = xT + (size_t)z * M2;
    int n0 = blockIdx.x * 32, k0 = blockIdx.y * 32;
    int tx = threadIdx.x, ty = threadIdx.y;  // 32 x 8
#pragma unroll
    for (int i = 0; i < 4; i++)
        tile[ty + i * 8][tx] = xb[(size_t)(k0 + ty + i * 8) * CD + n0 + tx];
    __syncthreads();
#pragma unroll
    for (int i = 0; i < 4; i++)
        xTb[(size_t)(n0 + ty + i * 8) * CD + k0 + tx] = (_Float16)tile[tx][ty + i * 8];
}

// ---------------------------------------------------------------------------
// Row softmax over ST (f32, rows are fixed d, reduce over c) -> attnT (f16)
// ---------------------------------------------------------------------------
__global__ __launch_bounds__(256) void softmax_col(const float* __restrict__ ST,
                                                   _Float16* __restrict__ attnT) {
    int d = blockIdx.x, z = blockIdx.y;
    const float* row = ST + ((size_t)z * CD + d) * CD;
    _Float16* orow = attnT + ((size_t)z * CD + d) * CD;
    int t = threadIdx.x;
    float4v v = *(const float4v*)(row + t * 4);
    float mx = fmaxf(fmaxf(v[0], v[1]), fmaxf(v[2], v[3]));
#pragma unroll
    for (int o = 32; o > 0; o >>= 1) mx = fmaxf(mx, __shfl_xor(mx, o));
    __shared__ float redm[4], reds[4];
    int wave = t >> 6, lane = t & 63;
    if (lane == 0) redm[wave] = mx;
    __syncthreads();
    mx = fmaxf(fmaxf(redm[0], redm[1]), fmaxf(redm[2], redm[3]));
    float e[4];
    float s = 0.f;
#pragma unroll
    for (int i = 0; i < 4; i++) {
        e[i] = __expf(v[i] - mx);
        s += e[i];
    }
#pragma unroll
    for (int o = 32; o > 0; o >>= 1) s += __shfl_xor(s, o);
    if (lane == 0) reds[wave] = s;
    __syncthreads();
    s = reds[0] + reds[1] + reds[2] + reds[3];
    float inv = 1.0f / s;
    half4 ov;
#pragma unroll
    for (int i = 0; i < 4; i++) ov[i] = (_Float16)(e[i] * inv);
    *(half4*)(orow + t * 4) = ov;
}

// ---------------------------------------------------------------------------
// NT GEMM, 256x256, 4-buffer 3-deep pipeline, ONE barrier per K-tile.
// C[m][n] = sum_k A[m][k]*B[n][k], K=1024, BK=32, 32 K-tiles.
// 8 waves (2Mx4N), per-wave output 128x64 (acc[8][4]), 16x16x32 f16 MFMA.
// LDS: 4 K-tile buffers x (A 256x32 + B 256x32) f16 = 128 KiB; 1 block/CU.
//
// Per-tile schedule (4 gload_lds/tile/thread, in-order vmcnt retire):
//   top of t: outstanding stages {t,t+1,t+2} = 12 loads
//   vmcnt(8)   -> MY tile-t loads landed ({t+1,t+2} remain)
//   s_barrier  -> ALL waves' tile-t stages published
//   issue 12 ds_reads from buf[t&3] (a0-3, b0-3, a4-7)
//   STAGE tile t+3 -> buf[(t+3)&3] = buf[(t-1)&3]
//     (write-safe: every wave past the barrier finished t-1's MFMAs, hence
//      its t-1 ds_reads of that buffer)
//   32 MFMA; compiler emits COUNTED lgkmcnt per operand use (m97 evidence):
//     cluster m0-3 waits only reads 1-8; a4-7 latency hides under it.
// Tail: t=30 vmcnt(4), t=31 vmcnt(0). Prologue stages tiles 0,1,2.
// Swizzle (r3-verified conflict-free; LDS[r][c8]=global[c8^(((r&15)>>1)&3)]):
//   stage source col = ((lane&3) ^ ((lane>>3)&3))*8, linear LDS dest;
//   read col = kq ^ (((rl>>1)&3)<<3)  [all frag-read rows have row&15==rl].
// ---------------------------------------------------------------------------
enum { EP_F16B = 0, EP_F32 = 1, EP_F16 = 2, EP_FIN = 3 };

#define STAGE_A(T, BUF)                                                        \
    GLD16(gA0 + (size_t)(T) * 32, &As[BUF][wv * 16][0]);                       \
    GLD16(gA1 + (size_t)(T) * 32, &As[BUF][128 + wv * 16][0]);
#define STAGE_B(T, BUF)                                                        \
    GLD16(gB0 + (size_t)(T) * 32, &Bs[BUF][wv * 16][0]);                       \
    GLD16(gB1 + (size_t)(T) * 32, &Bs[BUF][128 + wv * 16][0]);

#define TILE(BUF, DOSTAGE, STT, STBUF, VMSTR)                                  \
    {                                                                          \
        asm volatile("s_waitcnt " VMSTR ::: "memory");                         \
        __builtin_amdgcn_sched_barrier(0);                                     \
        __builtin_amdgcn_s_barrier();                                          \
        _Pragma("unroll") for (int m = 0; m < 4; m++)                          \
            a[m] = *(const half8*)&As[BUF][wr * 128 + m * 16 + rl][kqa];       \
        _Pragma("unroll") for (int n = 0; n < 4; n++)                          \
            b[n] = *(const half8*)&Bs[BUF][wc * 64 + n * 16 + rl][kqa];        \
        _Pragma("unroll") for (int m = 4; m < 8; m++)                          \
            a[m] = *(const half8*)&As[BUF][wr * 128 + m * 16 + rl][kqa];       \
        if (DOSTAGE) { STAGE_A(STT, STBUF) STAGE_B(STT, STBUF) }               \
        __builtin_amdgcn_sched_barrier(0);                                     \
        __builtin_amdgcn_s_setprio(1);                                         \
        _Pragma("unroll") for (int m = 0; m < 8; m++)                          \
            _Pragma("unroll") for (int n = 0; n < 4; n++)                      \
                acc[m][n] = __builtin_amdgcn_mfma_f32_16x16x32_f16(            \
                    a[m], b[n], acc[m][n], 0, 0, 0);                           \
        __builtin_amdgcn_s_setprio(0);                                         \
    }

template <int EPI>
__global__ __launch_bounds__(512, 2) void gemm_nt(
    const _Float16* __restrict__ A, int64_t sA, const _Float16* __restrict__ B, int64_t sB,
    void* __restrict__ Cp, int64_t sC, const float* __restrict__ bias,
    const float* __restrict__ bc, const float* __restrict__ gamma,
    const float* __restrict__ beta, const float* __restrict__ rmean,
    const float* __restrict__ rvar, const float* __restrict__ xres) {
    __shared__ __align__(16) _Float16 As[4][256][32];
    __shared__ __align__(16) _Float16 Bs[4][256][32];
    int z = blockIdx.z;
    const _Float16* Ab = A + (size_t)z * sA;
    const _Float16* Bb = B + (size_t)z * sB;
    int row0 = blockIdx.y * 256, col0 = blockIdx.x * 256;
    int tid = threadIdx.x, lane = tid & 63, wv = tid >> 6;
    int wr = wv >> 2, wc = wv & 3;

    // Staging: issue i covers rows [i*128 + wv*16, +16); lane l -> row + l/4,
    // source col pre-swizzled (LDS dest stays linear).
    const int srow = wv * 16 + (lane >> 2);
    const int scol = ((lane & 3) ^ ((lane >> 3) & 3)) * 8;
    const _Float16* gA0 = Ab + (size_t)(row0 + srow) * 1024 + scol;
    const _Float16* gA1 = gA0 + (size_t)128 * 1024;
    const _Float16* gB0 = Bb + (size_t)(col0 + srow) * 1024 + scol;
    const _Float16* gB1 = gB0 + (size_t)128 * 1024;

    const int rl = lane & 15;
    const int kq = (lane >> 4) * 8;
    const int kqa = kq ^ (((rl >> 1) & 3) << 3);  // read-side swizzle

    float4v acc[8][4] = {};
    half8 a[8], b[4];

    // Prologue: stage tiles 0,1,2 (12 gloads; oldest 4 = tile 0).
    STAGE_A(0, 0) STAGE_B(0, 0)
    STAGE_A(1, 1) STAGE_B(1, 1)
    STAGE_A(2, 2) STAGE_B(2, 2)

#pragma unroll 1
    for (int g = 0; g < 7; ++g) {  // tiles 4g..4g+3, stage 4g+3..4g+6
        int t = g * 4;
        TILE(0, 1, t + 3, 3, "vmcnt(8)")
        TILE(1, 1, t + 4, 0, "vmcnt(8)")
        TILE(2, 1, t + 5, 1, "vmcnt(8)")
        TILE(3, 1, t + 6, 2, "vmcnt(8)")
    }
    // Tiles 28..31 (t=28 stages tile 31).
    TILE(0, 1, 31, 3, "vmcnt(8)")
    TILE(1, 0, 0, 0, "vmcnt(8)")
    TILE(2, 0, 0, 0, "vmcnt(4)")
    TILE(3, 0, 0, 0, "vmcnt(0)")

    // Epilogue. C/D layout: col = lane&15, row = (lane>>4)*4 + reg  [m89]
#pragma unroll
    for (int m = 0; m < 8; m++) {
#pragma unroll
        for (int r = 0; r < 4; r++) {
            int row = row0 + wr * 128 + m * 16 + ((lane >> 4) << 2) + r;
            float add0 = 0.f, mu = 0.f, invs = 1.f, bet = 0.f;
            if constexpr (EPI == EP_F16B) add0 = bias[row];
            if constexpr (EPI == EP_FIN) {
                add0 = bc[row];
                mu = rmean[row];
                invs = gamma[row] * rsqrtf(rvar[row] + 1e-5f);
                bet = beta[row];
            }
#pragma unroll
            for (int n = 0; n < 4; n++) {
                int col = col0 + wc * 64 + n * 16 + (lane & 15);
                float v = acc[m][n][r];
                if constexpr (EPI == EP_F16B) {
                    ((_Float16*)Cp)[(size_t)z * sC + (size_t)row * 1024 + col] = (_Float16)(v + add0);
                } else if constexpr (EPI == EP_F32) {
                    ((float*)Cp)[(size_t)z * sC + (size_t)row * 1024 + col] = v;
                } else if constexpr (EPI == EP_F16) {
                    ((_Float16*)Cp)[(size_t)z * sC + (size_t)row * 1024 + col] = (_Float16)v;
                } else {
                    v += add0;
                    v = v >= 0.f ? v : 0.01f * v;
                    v = (v - mu) * invs + bet;
                    v += xres[(size_t)z * M2 + (size_t)row * 1024 + col];
                    ((float*)Cp)[(size_t)z * sC + (size_t)row * 1024 + col] = v;
                }
            }
        }
    }
}

// ---------------------------------------------------------------------------
extern "C" void kernel_launch(void* const* d_in, const int* in_sizes, int n_in,
                              void* d_out, int out_size, void* d_ws, size_t ws_size,
                              hipStream_t stream) {
    const float* x = (const float*)d_in[0];
    const float* Wf = (const float*)d_in[1];
    const float* bf = (const float*)d_in[2];
    const float* Wg = (const float*)d_in[3];
    const float* bg = (const float*)d_in[4];
    const float* Wh = (const float*)d_in[5];
    const float* bh = (const float*)d_in[6];
    const float* Wc = (const float*)d_in[7];
    const float* bc = (const float*)d_in[8];
    const float* gamma = (const float*)d_in[9];
    const float* beta = (const float*)d_in[10];
    const float* rmean = (const float*)d_in[11];
    const float* rvar = (const float*)d_in[12];

    // Fixed ws region: Wfgh f16 (6MB) + Wc f16 (2MB) + bias stack
    char* p = (char*)d_ws;
    _Float16* Wfgh = (_Float16*)p;
    p += (size_t)3 * M2 * 2;
    _Float16* WcH = (_Float16*)p;
    p += (size_t)M2 * 2;
    float* bstack = (float*)p;
    p += (size_t)3 * CD * 4;
    size_t fixed = (size_t)(p - (char*)d_ws);
    fixed = (fixed + 255) & ~(size_t)255;

    // Per-batch region: xT f16 (2MB, reused as attnT) + FGH f16 (6MB) +
    // ST f32 (4MB, reused as hfgT f16). 12 MiB per batch.
    size_t perB = (size_t)2 * M2 + (size_t)6 * M2 + (size_t)4 * M2;
    int nb = 16;
    while (nb > 1 && fixed + (size_t)nb * perB > ws_size) nb >>= 1;

    {
        int total = 4 * M2 + 3 * CD;
        prep_weights<<<dim3((total + 255) / 256), dim3(256), 0, stream>>>(
            Wf, Wg, Wh, Wc, bf, bg, bh, Wfgh, WcH, bstack);
    }

    for (int b0 = 0; b0 < 16; b0 += nb) {
        char* q = (char*)d_ws + fixed;
        _Float16* xT = (_Float16*)q;
        _Float16* FGH = (_Float16*)(q + (size_t)nb * 2 * M2);
        float* ST = (float*)(q + (size_t)nb * 8 * M2);
        _Float16* attnT = xT;          // xT dead after GEMM1
        _Float16* hfgT = (_Float16*)ST;  // ST dead after softmax

        // xT[z][n][k] = x[b0+z][k][n]
        transpose_x<<<dim3(32, 32, nb), dim3(32, 8), 0, stream>>>(x, xT, b0);
        // FGH[z] (3072 x 1024) = Wfgh (3072x1024) . xT[z]^T  + bias
        gemm_nt<EP_F16B><<<dim3(4, 12, nb), dim3(512), 0, stream>>>(
            Wfgh, 0, xT, M2, FGH, (int64_t)3 * M2, bstack,
            nullptr, nullptr, nullptr, nullptr, nullptr, nullptr);
        // ST[z][d][c] = sum_n G[d][n] F[c][n]
        gemm_nt<EP_F32><<<dim3(4, 4, nb), dim3(512), 0, stream>>>(
            FGH + M2, (int64_t)3 * M2, FGH, (int64_t)3 * M2, ST, M2,
            nullptr, nullptr, nullptr, nullptr, nullptr, nullptr, nullptr);
        // attnT[z][d][c] = softmax over c of ST[z][d][:]
        softmax_col<<<dim3(1024, nb), dim3(256), 0, stream>>>(ST, attnT);
        // hfgT[z][d][c] = sum_n attnT[d][n] H[c][n]
        gemm_nt<EP_F16><<<dim3(4, 4, nb), dim3(512), 0, stream>>>(
            attnT, M2, FGH + 2 * M2, (int64_t)3 * M2, hfgT, M2,
            nullptr, nullptr, nullptr, nullptr, nullptr, nullptr, nullptr);
        // out[b][o][d] = BN(leaky(Wc . hfgT^T + bc)) + x
        gemm_nt<EP_FIN><<<dim3(4, 4, nb), dim3(512), 0, stream>>>(
            WcH, 0, hfgT, M2, (float*)d_out + (size_t)b0 * M2, M2,
            nullptr, bc, gamma, beta, rmean, rvar, x + (size_t)b0 * M2);
    }
}